// Round 8
// baseline (643.031 us; speedup 1.0000x reference)
//
#include <hip/hip_runtime.h>
#include <math.h>

#define FDIM 64
#define HDIM 128

typedef __attribute__((ext_vector_type(8)))  short v8s;
typedef __attribute__((ext_vector_type(16))) float f32x16;

#define MFMA32(a,b,c) __builtin_amdgcn_mfma_f32_32x32x16_bf16(a,b,c,0,0,0)

// ---- fp32 -> bf16 hi/lo split helpers
__device__ __forceinline__ unsigned short bf_hi(float v){
    return (unsigned short)(__float_as_uint(v) >> 16);
}
__device__ __forceinline__ float hi_part(float v){
    return __uint_as_float(__float_as_uint(v) & 0xFFFF0000u);
}
__device__ __forceinline__ unsigned short bf_rnd(float v){
    return (unsigned short)((__float_as_uint(v) + 0x8000u) >> 16);
}

// split 8 fp32 -> bf16 hi frag + lo frag (in registers)
__device__ __forceinline__ void split8(const float* x, v8s& ah, v8s& al){
    #pragma unroll
    for (int j = 0; j < 8; ++j){
        unsigned u = __float_as_uint(x[j]);
        ((unsigned short*)&ah)[j] = (unsigned short)(u >> 16);
        float rem = x[j] - __uint_as_float(u & 0xFFFF0000u);
        ((unsigned short*)&al)[j] = (unsigned short)((__float_as_uint(rem) + 0x8000u) >> 16);
    }
}

// ---- branchless gelu: 0.5x(1+erf(x/sqrt2)), erf via A&S 7.1.26 (|err|<1.5e-7)
__device__ __forceinline__ float gelu_fast(float x){
    float z = fminf(fabsf(x) * 0.70710678118654752440f, 4.0f);
    float t = __builtin_amdgcn_rcpf(fmaf(0.3275911f, z, 1.0f));
    float p = fmaf(t, 1.061405429f, -1.453152027f);
    p = fmaf(t, p, 1.421413741f);
    p = fmaf(t, p, -0.284496736f);
    p = fmaf(t, p, 0.254829592f);
    float r  = t * p;
    float ez = __expf(-z * z);
    float erfv = fmaf(-r, ez, 1.0f);
    erfv = copysignf(erfv, x);
    float hx = 0.5f * x;
    return fmaf(hx, erfv, hx);
}

// ---- cross-half exchange: X holds rows r+4hf, Y holds rows r+8+4hf of a 16-row group.
// After: X = j-value (rows 0..3 for hf0 / 8..11 for hf1), Y = j+4 value (4..7 / 12..15),
// i.e. each lane ends with 8 CONSECUTIVE rows split as {X(j), Y(j+4)}.
// Portable form (2 shfl + 2 select); v_permlane32_swap is the 1-inst upgrade later.
__device__ __forceinline__ void xpair(float& xv, float& yv, bool lowhalf){
    float xs = __shfl_xor(xv, 32);
    float ys = __shfl_xor(yv, 32);
    float a = lowhalf ? xv : ys;
    float b = lowhalf ? xs : yv;
    xv = a; yv = b;
}

// =====================================================================================
// Prep kernel: split W1..W4 into hi/lo bf16, MFMA B-fragment order (unchanged), PLUS
// biases permuted into C/D-fragment order: bp[block*32 + hf*16 + g] =
// b[block*32 + (g&3) + 8*(g>>2) + 4*hf]  (so acc-init is 4 contiguous float4 per lane).
// ws layout: wf = 81920 u16 (163840 B), then 448 f32 bias-perm (1792 B). Needs 165632 B.
// =====================================================================================
__global__ void prep_w(const float* __restrict__ W1, const float* __restrict__ W2,
                       const float* __restrict__ W3, const float* __restrict__ W4,
                       const float* __restrict__ b1, const float* __restrict__ b2,
                       const float* __restrict__ b3, const float* __restrict__ b4,
                       unsigned short* __restrict__ wf)
{
    int idx = blockIdx.x * 256 + threadIdx.x;
    if (idx < 40960){
        const float* W; int N, KS, ub, local;
        if (idx < 8192)       { W = W1; N = HDIM; KS = 4; ub = 0;     local = idx;         }
        else if (idx < 16384) { W = W2; N = FDIM; KS = 8; ub = 16384; local = idx - 8192;  }
        else if (idx < 24576) { W = W3; N = HDIM; KS = 4; ub = 32768; local = idx - 16384; }
        else                  { W = W4; N = HDIM; KS = 8; ub = 49152; local = idx - 24576; }
        int tile   = local >> 9;
        int within = local & 511;
        int l = within >> 3, j = within & 7;
        int ks = tile % KS, nt = tile / KS;
        int k = ks * 16 + (l >> 5) * 8 + j;
        int n = nt * 32 + (l & 31);
        float v = W[k * N + n];
        float rem = v - hi_part(v);
        wf[ub + tile * 1024 +       l * 8 + j] = bf_hi(v);
        wf[ub + tile * 1024 + 512 + l * 8 + j] = bf_rnd(rem);
        return;
    }
    int j = idx - 40960;
    if (j >= 448) return;
    float* bp = (float*)(wf + 81920);
    const float* b; int base;
    if (j < 128)      { b = b1; base = 0;   }
    else if (j < 192) { b = b2; base = 128; j -= 128; }
    else if (j < 320) { b = b3; base = 192; j -= 192; }
    else              { b = b4; base = 320; j -= 320; }
    int block = j >> 5, r = j & 31;
    int hf = r >> 4, c = (r >> 2) & 3, i = r & 3;
    bp[base + block * 32 + r] = b[block * 32 + c * 8 + hf * 4 + i];
}

// =====================================================================================
// Main kernel: 1 wave = 1 block = 32 edges, ZERO LDS.
// Every GEMM computed operand-swapped: D = W^T X^T via MFMA32(w_frag, x_frag, acc)
// (A-frag of M == B-frag of M^T for 32x32x16, so prep tables & per-lane data unchanged).
// Output lands lane=edge; next GEMM's fragments rebuilt with xpair cross-half exchange.
// No LDS round-trips, no lgkmcnt stalls, no stage-0 broadcast loop.
// =====================================================================================
__global__ __launch_bounds__(64, 2)
void arn_mfma(const float* __restrict__ known_mask,
              const int*   __restrict__ obs_idx,
              const int*   __restrict__ obs_mask_idx,
              const int*   __restrict__ attr_idx,
              const float* __restrict__ obs_embs,
              const float* __restrict__ fea_corr,
              const unsigned short* __restrict__ wf,
              float* __restrict__ out, int E)
{
    const int lane = threadIdx.x;          // 0..63
    const int cl = lane & 31;
    const int hf = lane >> 5;
    const bool lh = (hf == 0);
    const long long ebase = (long long)blockIdx.x * 32;
    const long long e0 = ebase + cl;       // this lane's edge (both hf halves: same edge)
    const int ec = (e0 < (long long)E) ? (int)e0 : (E - 1);

    const int attrv = attr_idx[ec];
    const int mrowv = obs_mask_idx[ec];
    const int obsIv = obs_idx[ec];

    const float* bp  = (const float*)(wf + 81920);

    // ---- stage 0: per-lane gather of own edge's mask features (B-frag order:
    //      lane (cl,hf) holds S[cl][k], k = ks*16 + hf*8 + j), mask, softmax in-lane.
    float x[32];
    {
        const float* kr = known_mask + (long long)mrowv * FDIM + hf * 8;
        #pragma unroll
        for (int ks = 0; ks < 4; ++ks){
            float4 a0 = *(const float4*)(kr + ks * 16);
            float4 a1 = *(const float4*)(kr + ks * 16 + 4);
            x[ks*8+0]=a0.x; x[ks*8+1]=a0.y; x[ks*8+2]=a0.z; x[ks*8+3]=a0.w;
            x[ks*8+4]=a1.x; x[ks*8+5]=a1.y; x[ks*8+6]=a1.z; x[ks*8+7]=a1.w;
        }
        const int fb = hf * 8;
        #pragma unroll
        for (int ks = 0; ks < 4; ++ks)
            #pragma unroll
            for (int i = 0; i < 8; ++i)
                x[ks*8+i] = (ks*16 + fb + i == attrv) ? 0.f : x[ks*8+i];
        float mx = x[0];
        #pragma unroll
        for (int i = 1; i < 32; ++i) mx = fmaxf(mx, x[i]);
        mx = fmaxf(mx, __shfl_xor(mx, 32));
        float s = 0.f;
        #pragma unroll
        for (int i = 0; i < 32; ++i){ x[i] = __expf(x[i] - mx); s += x[i]; }
        s += __shfl_xor(s, 32);
        float rs = __builtin_amdgcn_rcpf(s);
        #pragma unroll
        for (int i = 0; i < 32; ++i) x[i] *= rs;
    }
    v8s sa[4], sl[4];
    #pragma unroll
    for (int ks = 0; ks < 4; ++ks) split8(&x[ks*8], sa[ks], sl[ks]);

    // ---- GEMM1 (swapped): h1^T = W1^T S^T, 4 out-feature blocks; gelu on acc
    f32x16 acc1[4];
    #pragma unroll
    for (int nt = 0; nt < 4; ++nt){
        const float* bb = bp + 0 + nt * 32 + hf * 16;
        f32x16 a;
        #pragma unroll
        for (int g = 0; g < 16; ++g) a[g] = bb[g];
        __builtin_amdgcn_s_setprio(1);
        #pragma unroll
        for (int ks = 0; ks < 4; ++ks){
            const v8s* wp = (const v8s*)(wf + (nt * 4 + ks) * 1024);
            v8s bh = wp[lane], bl = wp[lane + 64];
            a = MFMA32(bh, sa[ks], a);
            a = MFMA32(bl, sa[ks], a);
            a = MFMA32(bh, sl[ks], a);
        }
        __builtin_amdgcn_s_setprio(0);
        #pragma unroll
        for (int g = 0; g < 16; ++g) a[g] = gelu_fast(a[g]);
        acc1[nt] = a;
    }

    // ---- exchange -> h1 fragments (lane holds 8 consecutive features per ks-group)
    v8s ha[8], hl[8];
    #pragma unroll
    for (int nt = 0; nt < 4; ++nt){
        #pragma unroll
        for (int sg = 0; sg < 2; ++sg){
            float xx[8];
            #pragma unroll
            for (int i = 0; i < 4; ++i){ xx[i] = acc1[nt][sg*8+i]; xx[4+i] = acc1[nt][sg*8+4+i]; }
            #pragma unroll
            for (int i = 0; i < 4; ++i) xpair(xx[i], xx[4+i], lh);
            split8(xx, ha[nt*2+sg], hl[nt*2+sg]);
        }
    }

    // ---- GEMM2 (swapped): t^T = W2^T h1^T (2 blocks); gelu
    f32x16 acc2[2];
    #pragma unroll
    for (int nt = 0; nt < 2; ++nt){
        const float* bb = bp + 128 + nt * 32 + hf * 16;
        f32x16 a;
        #pragma unroll
        for (int g = 0; g < 16; ++g) a[g] = bb[g];
        __builtin_amdgcn_s_setprio(1);
        #pragma unroll
        for (int ks = 0; ks < 8; ++ks){
            const v8s* wp = (const v8s*)(wf + 16384 + (nt * 8 + ks) * 1024);
            v8s bh = wp[lane], bl = wp[lane + 64];
            a = MFMA32(bh, ha[ks], a);
            a = MFMA32(bl, ha[ks], a);
            a = MFMA32(bh, hl[ks], a);
        }
        __builtin_amdgcn_s_setprio(0);
        #pragma unroll
        for (int g = 0; g < 16; ++g) a[g] = gelu_fast(a[g]);
        acc2[nt] = a;
    }

    // ---- exchange + fea_corr (features now consecutive -> float4 loads) -> t frags
    const float* fcrow = fea_corr + (long long)attrv * FDIM;
    v8s ta[4], tl[4];
    #pragma unroll
    for (int nt = 0; nt < 2; ++nt){
        #pragma unroll
        for (int sg = 0; sg < 2; ++sg){
            float xx[8];
            #pragma unroll
            for (int i = 0; i < 4; ++i){ xx[i] = acc2[nt][sg*8+i]; xx[4+i] = acc2[nt][sg*8+4+i]; }
            #pragma unroll
            for (int i = 0; i < 4; ++i) xpair(xx[i], xx[4+i], lh);
            const float* fp = fcrow + nt * 32 + sg * 16 + hf * 8;
            float4 f0 = *(const float4*)(fp);
            float4 f1 = *(const float4*)(fp + 4);
            xx[0]*=f0.x; xx[1]*=f0.y; xx[2]*=f0.z; xx[3]*=f0.w;
            xx[4]*=f1.x; xx[5]*=f1.y; xx[6]*=f1.z; xx[7]*=f1.w;
            split8(xx, ta[nt*2+sg], tl[nt*2+sg]);
        }
    }

    // ---- GEMM3 (swapped): u^T = W3^T t^T (4 blocks); gelu
    f32x16 acc3[4];
    #pragma unroll
    for (int nt = 0; nt < 4; ++nt){
        const float* bb = bp + 192 + nt * 32 + hf * 16;
        f32x16 a;
        #pragma unroll
        for (int g = 0; g < 16; ++g) a[g] = bb[g];
        __builtin_amdgcn_s_setprio(1);
        #pragma unroll
        for (int ks = 0; ks < 4; ++ks){
            const v8s* wp = (const v8s*)(wf + 32768 + (nt * 4 + ks) * 1024);
            v8s bh = wp[lane], bl = wp[lane + 64];
            a = MFMA32(bh, ta[ks], a);
            a = MFMA32(bl, ta[ks], a);
            a = MFMA32(bh, tl[ks], a);
        }
        __builtin_amdgcn_s_setprio(0);
        #pragma unroll
        for (int g = 0; g < 16; ++g) a[g] = gelu_fast(a[g]);
        acc3[nt] = a;
    }

    // ---- exchange + obs_embs multiply (consecutive features -> float4) -> u frags
    const float* obrow = obs_embs + (long long)obsIv * HDIM;
    v8s ua[8], ul[8];
    #pragma unroll
    for (int nt = 0; nt < 4; ++nt){
        #pragma unroll
        for (int sg = 0; sg < 2; ++sg){
            float xx[8];
            #pragma unroll
            for (int i = 0; i < 4; ++i){ xx[i] = acc3[nt][sg*8+i]; xx[4+i] = acc3[nt][sg*8+4+i]; }
            #pragma unroll
            for (int i = 0; i < 4; ++i) xpair(xx[i], xx[4+i], lh);
            const float* op = obrow + nt * 32 + sg * 16 + hf * 8;
            float4 o0 = *(const float4*)(op);
            float4 o1 = *(const float4*)(op + 4);
            xx[0]*=o0.x; xx[1]*=o0.y; xx[2]*=o0.z; xx[3]*=o0.w;
            xx[4]*=o1.x; xx[5]*=o1.y; xx[6]*=o1.z; xx[7]*=o1.w;
            split8(xx, ua[nt*2+sg], ul[nt*2+sg]);
        }
    }

    // ---- GEMM4 (swapped, streamed per block): out^T = W4^T u^T; gelu; exchange; store
    const bool valid = (e0 < (long long)E);
    float* orow = out + e0 * HDIM;
    #pragma unroll
    for (int nt = 0; nt < 4; ++nt){
        const float* bb = bp + 320 + nt * 32 + hf * 16;
        f32x16 a;
        #pragma unroll
        for (int g = 0; g < 16; ++g) a[g] = bb[g];
        __builtin_amdgcn_s_setprio(1);
        #pragma unroll
        for (int ks = 0; ks < 8; ++ks){
            const v8s* wp = (const v8s*)(wf + 49152 + (nt * 8 + ks) * 1024);
            v8s bh = wp[lane], bl = wp[lane + 64];
            a = MFMA32(bh, ua[ks], a);
            a = MFMA32(bl, ua[ks], a);
            a = MFMA32(bh, ul[ks], a);
        }
        __builtin_amdgcn_s_setprio(0);
        #pragma unroll
        for (int g = 0; g < 16; ++g) a[g] = gelu_fast(a[g]);
        #pragma unroll
        for (int sg = 0; sg < 2; ++sg){
            float xx[8];
            #pragma unroll
            for (int i = 0; i < 4; ++i){ xx[i] = a[sg*8+i]; xx[4+i] = a[sg*8+4+i]; }
            #pragma unroll
            for (int i = 0; i < 4; ++i) xpair(xx[i], xx[4+i], lh);
            if (valid){
                float4 v0; v0.x=xx[0]; v0.y=xx[1]; v0.z=xx[2]; v0.w=xx[3];
                float4 v1; v1.x=xx[4]; v1.y=xx[5]; v1.z=xx[6]; v1.w=xx[7];
                float* dst = orow + nt * 32 + sg * 16 + hf * 8;
                *(float4*)(dst)     = v0;
                *(float4*)(dst + 4) = v1;
            }
        }
    }
}

extern "C" void kernel_launch(void* const* d_in, const int* in_sizes, int n_in,
                              void* d_out, int out_size, void* d_ws, size_t ws_size,
                              hipStream_t stream)
{
    (void)n_in; (void)out_size; (void)ws_size;   // requires ws_size >= 165632 B
    const float* known_mask   = (const float*)d_in[0];
    const int*   obs_idx      = (const int*)d_in[1];
    const int*   obs_mask_idx = (const int*)d_in[2];
    const int*   attr_idx     = (const int*)d_in[3];
    const float* obs_embs     = (const float*)d_in[4];
    const float* fea_corr     = (const float*)d_in[5];
    const float* W_rm1 = (const float*)d_in[6];
    const float* b_rm1 = (const float*)d_in[7];
    const float* W_rm2 = (const float*)d_in[8];
    const float* b_rm2 = (const float*)d_in[9];
    const float* W_rr  = (const float*)d_in[10];
    const float* b_rr  = (const float*)d_in[11];
    const float* W_rc  = (const float*)d_in[12];
    const float* b_rc  = (const float*)d_in[13];

    unsigned short* wf = (unsigned short*)d_ws;
    const int E = in_sizes[1];

    hipLaunchKernelGGL(prep_w, dim3(162), dim3(256), 0, stream,
                       W_rm1, W_rm2, W_rr, W_rc,
                       b_rm1, b_rm2, b_rr, b_rc, wf);

    const int blocks = (E + 31) / 32;   // 32 edges per 1-wave block, zero LDS
    hipLaunchKernelGGL(arn_mfma, dim3(blocks), dim3(64), 0, stream,
                       known_mask, obs_idx, obs_mask_idx, attr_idx,
                       obs_embs, fea_corr,
                       wf, (float*)d_out, E);
}

// Round 9
// 624.653 us; speedup vs baseline: 1.0294x; 1.0294x over previous
//
#include <hip/hip_runtime.h>
#include <math.h>

#define FDIM 64
#define HDIM 128

typedef __attribute__((ext_vector_type(8)))  short v8s;
typedef __attribute__((ext_vector_type(16))) float f32x16;

#define MFMA32(a,b,c) __builtin_amdgcn_mfma_f32_32x32x16_bf16(a,b,c,0,0,0)

// ---- fp32 -> bf16 hi/lo split helpers
__device__ __forceinline__ unsigned short bf_hi(float v){
    return (unsigned short)(__float_as_uint(v) >> 16);
}
__device__ __forceinline__ float hi_part(float v){
    return __uint_as_float(__float_as_uint(v) & 0xFFFF0000u);
}
__device__ __forceinline__ unsigned short bf_rnd(float v){
    return (unsigned short)((__float_as_uint(v) + 0x8000u) >> 16);
}

// split 8 fp32 -> bf16 hi frag + lo frag (in registers)
__device__ __forceinline__ void split8(const float* x, v8s& ah, v8s& al){
    #pragma unroll
    for (int j = 0; j < 8; ++j){
        unsigned u = __float_as_uint(x[j]);
        ((unsigned short*)&ah)[j] = (unsigned short)(u >> 16);
        float rem = x[j] - __uint_as_float(u & 0xFFFF0000u);
        ((unsigned short*)&al)[j] = (unsigned short)((__float_as_uint(rem) + 0x8000u) >> 16);
    }
}

// ---- branchless gelu: 0.5x(1+erf(x/sqrt2)), erf via A&S 7.1.26 (|err|<1.5e-7)
__device__ __forceinline__ float gelu_fast(float x){
    float z = fminf(fabsf(x) * 0.70710678118654752440f, 4.0f);
    float t = __builtin_amdgcn_rcpf(fmaf(0.3275911f, z, 1.0f));
    float p = fmaf(t, 1.061405429f, -1.453152027f);
    p = fmaf(t, p, 1.421413741f);
    p = fmaf(t, p, -0.284496736f);
    p = fmaf(t, p, 0.254829592f);
    float r  = t * p;
    float ez = __expf(-z * z);
    float erfv = fmaf(-r, ez, 1.0f);
    erfv = copysignf(erfv, x);
    float hx = 0.5f * x;
    return fmaf(hx, erfv, hx);
}

// ---- cross-half exchange (verified r8): after call, lane holds 8 consecutive rows
__device__ __forceinline__ void xpair(float& xv, float& yv, bool lowhalf){
    float xs = __shfl_xor(xv, 32);
    float ys = __shfl_xor(yv, 32);
    float a = lowhalf ? xv : ys;
    float b = lowhalf ? xs : yv;
    xv = a; yv = b;
}

// =====================================================================================
// Prep kernel (unchanged from r8): W1..W4 hi/lo bf16 B-fragment tables + biases
// permuted into C/D-fragment order. ws: 81920 u16 + 448 f32 = 165632 B.
// =====================================================================================
__global__ void prep_w(const float* __restrict__ W1, const float* __restrict__ W2,
                       const float* __restrict__ W3, const float* __restrict__ W4,
                       const float* __restrict__ b1, const float* __restrict__ b2,
                       const float* __restrict__ b3, const float* __restrict__ b4,
                       unsigned short* __restrict__ wf)
{
    int idx = blockIdx.x * 256 + threadIdx.x;
    if (idx < 40960){
        const float* W; int N, KS, ub, local;
        if (idx < 8192)       { W = W1; N = HDIM; KS = 4; ub = 0;     local = idx;         }
        else if (idx < 16384) { W = W2; N = FDIM; KS = 8; ub = 16384; local = idx - 8192;  }
        else if (idx < 24576) { W = W3; N = HDIM; KS = 4; ub = 32768; local = idx - 16384; }
        else                  { W = W4; N = HDIM; KS = 8; ub = 49152; local = idx - 24576; }
        int tile   = local >> 9;
        int within = local & 511;
        int l = within >> 3, j = within & 7;
        int ks = tile % KS, nt = tile / KS;
        int k = ks * 16 + (l >> 5) * 8 + j;
        int n = nt * 32 + (l & 31);
        float v = W[k * N + n];
        float rem = v - hi_part(v);
        wf[ub + tile * 1024 +       l * 8 + j] = bf_hi(v);
        wf[ub + tile * 1024 + 512 + l * 8 + j] = bf_rnd(rem);
        return;
    }
    int j = idx - 40960;
    if (j >= 448) return;
    float* bp = (float*)(wf + 81920);
    const float* b; int base;
    if (j < 128)      { b = b1; base = 0;   }
    else if (j < 192) { b = b2; base = 128; j -= 128; }
    else if (j < 320) { b = b3; base = 192; j -= 192; }
    else              { b = b4; base = 320; j -= 320; }
    int block = j >> 5, r = j & 31;
    int hf = r >> 4, c = (r >> 2) & 3, i = r & 3;
    bp[base + block * 32 + r] = b[block * 32 + c * 8 + hf * 4 + i];
}

// =====================================================================================
// Main kernel: 256-thread WG = 4 FULLY INDEPENDENT waves, each one 32-edge tile
// (tile = bid*4 + wid). ZERO LDS, no barriers. Operand-swapped MFMA (r8 scheme:
// D = W^T X^T, output lane=edge, xpair exchange between GEMMs).
// r8 lesson: residency tracks WG slots (~7-8/CU), not waves -> pack 4 waves/WG.
// Spill fix vs r8: per-tile fusion (MFMA -> gelu -> exchange -> split in one nt
// iteration) keeps a single f32x16 acc live instead of acc[4] arrays.
// __launch_bounds__(256,4) -> VGPR cap 128 (= 4 waves/SIMD, 16 waves/CU).
// =====================================================================================
__global__ __launch_bounds__(256, 4)
void arn_mfma(const float* __restrict__ known_mask,
              const int*   __restrict__ obs_idx,
              const int*   __restrict__ obs_mask_idx,
              const int*   __restrict__ attr_idx,
              const float* __restrict__ obs_embs,
              const float* __restrict__ fea_corr,
              const unsigned short* __restrict__ wf,
              float* __restrict__ out, int E)
{
    const int wid  = threadIdx.x >> 6;     // 0..3: independent wave
    const int lane = threadIdx.x & 63;
    const int cl = lane & 31;
    const int hf = lane >> 5;
    const bool lh = (hf == 0);
    const long long ebase = ((long long)blockIdx.x * 4 + wid) * 32;
    if (ebase >= (long long)E) return;     // tail waves idle (no barriers -> safe)
    const long long e0 = ebase + cl;
    const int ec = (e0 < (long long)E) ? (int)e0 : (E - 1);

    const int attrv = attr_idx[ec];
    const int mrowv = obs_mask_idx[ec];
    const int obsIv = obs_idx[ec];

    const float* bp = (const float*)(wf + 81920);

    // ---- stage 0: per-lane gather of own edge's mask row (B-frag order), softmax
    float x[32];
    {
        const float* kr = known_mask + (long long)mrowv * FDIM + hf * 8;
        #pragma unroll
        for (int ks = 0; ks < 4; ++ks){
            float4 a0 = *(const float4*)(kr + ks * 16);
            float4 a1 = *(const float4*)(kr + ks * 16 + 4);
            x[ks*8+0]=a0.x; x[ks*8+1]=a0.y; x[ks*8+2]=a0.z; x[ks*8+3]=a0.w;
            x[ks*8+4]=a1.x; x[ks*8+5]=a1.y; x[ks*8+6]=a1.z; x[ks*8+7]=a1.w;
        }
        const int fb = hf * 8;
        #pragma unroll
        for (int ks = 0; ks < 4; ++ks)
            #pragma unroll
            for (int i = 0; i < 8; ++i)
                x[ks*8+i] = (ks*16 + fb + i == attrv) ? 0.f : x[ks*8+i];
        float mx = x[0];
        #pragma unroll
        for (int i = 1; i < 32; ++i) mx = fmaxf(mx, x[i]);
        mx = fmaxf(mx, __shfl_xor(mx, 32));
        float s = 0.f;
        #pragma unroll
        for (int i = 0; i < 32; ++i){ x[i] = __expf(x[i] - mx); s += x[i]; }
        s += __shfl_xor(s, 32);
        float rs = __builtin_amdgcn_rcpf(s);
        #pragma unroll
        for (int i = 0; i < 32; ++i) x[i] *= rs;
    }
    v8s sa[4], sl[4];
    #pragma unroll
    for (int ks = 0; ks < 4; ++ks) split8(&x[ks*8], sa[ks], sl[ks]);

    // ---- GEMM1 (swapped, fused per tile): h1 frags ha/hl
    v8s ha[8], hl[8];
    #pragma unroll
    for (int nt = 0; nt < 4; ++nt){
        const float* bb = bp + 0 + nt * 32 + hf * 16;
        f32x16 a;
        #pragma unroll
        for (int g = 0; g < 16; ++g) a[g] = bb[g];
        __builtin_amdgcn_s_setprio(1);
        #pragma unroll
        for (int ks = 0; ks < 4; ++ks){
            const v8s* wp = (const v8s*)(wf + (nt * 4 + ks) * 1024);
            v8s bh = wp[lane], bl = wp[lane + 64];
            a = MFMA32(bh, sa[ks], a);
            a = MFMA32(bl, sa[ks], a);
            a = MFMA32(bh, sl[ks], a);
        }
        __builtin_amdgcn_s_setprio(0);
        #pragma unroll
        for (int g = 0; g < 16; ++g) a[g] = gelu_fast(a[g]);
        #pragma unroll
        for (int sg = 0; sg < 2; ++sg){
            float xx[8];
            #pragma unroll
            for (int i = 0; i < 4; ++i){ xx[i] = a[sg*8+i]; xx[4+i] = a[sg*8+4+i]; }
            #pragma unroll
            for (int i = 0; i < 4; ++i) xpair(xx[i], xx[4+i], lh);
            split8(xx, ha[nt*2+sg], hl[nt*2+sg]);
        }
    }

    // ---- GEMM2 (swapped, fused): t frags ta/tl (with fea_corr fold)
    const float* fcrow = fea_corr + (long long)attrv * FDIM;
    v8s ta[4], tl[4];
    #pragma unroll
    for (int nt = 0; nt < 2; ++nt){
        const float* bb = bp + 128 + nt * 32 + hf * 16;
        f32x16 a;
        #pragma unroll
        for (int g = 0; g < 16; ++g) a[g] = bb[g];
        __builtin_amdgcn_s_setprio(1);
        #pragma unroll
        for (int ks = 0; ks < 8; ++ks){
            const v8s* wp = (const v8s*)(wf + 16384 + (nt * 8 + ks) * 1024);
            v8s bh = wp[lane], bl = wp[lane + 64];
            a = MFMA32(bh, ha[ks], a);
            a = MFMA32(bl, ha[ks], a);
            a = MFMA32(bh, hl[ks], a);
        }
        __builtin_amdgcn_s_setprio(0);
        #pragma unroll
        for (int g = 0; g < 16; ++g) a[g] = gelu_fast(a[g]);
        #pragma unroll
        for (int sg = 0; sg < 2; ++sg){
            float xx[8];
            #pragma unroll
            for (int i = 0; i < 4; ++i){ xx[i] = a[sg*8+i]; xx[4+i] = a[sg*8+4+i]; }
            #pragma unroll
            for (int i = 0; i < 4; ++i) xpair(xx[i], xx[4+i], lh);
            const float* fp = fcrow + nt * 32 + sg * 16 + hf * 8;
            float4 f0 = *(const float4*)(fp);
            float4 f1 = *(const float4*)(fp + 4);
            xx[0]*=f0.x; xx[1]*=f0.y; xx[2]*=f0.z; xx[3]*=f0.w;
            xx[4]*=f1.x; xx[5]*=f1.y; xx[6]*=f1.z; xx[7]*=f1.w;
            split8(xx, ta[nt*2+sg], tl[nt*2+sg]);
        }
    }

    // ---- GEMM3 (swapped, fused): u frags ua/ul (with obs_embs fold)
    const float* obrow = obs_embs + (long long)obsIv * HDIM;
    v8s ua[8], ul[8];
    #pragma unroll
    for (int nt = 0; nt < 4; ++nt){
        const float* bb = bp + 192 + nt * 32 + hf * 16;
        f32x16 a;
        #pragma unroll
        for (int g = 0; g < 16; ++g) a[g] = bb[g];
        __builtin_amdgcn_s_setprio(1);
        #pragma unroll
        for (int ks = 0; ks < 4; ++ks){
            const v8s* wp = (const v8s*)(wf + 32768 + (nt * 4 + ks) * 1024);
            v8s bh = wp[lane], bl = wp[lane + 64];
            a = MFMA32(bh, ta[ks], a);
            a = MFMA32(bl, ta[ks], a);
            a = MFMA32(bh, tl[ks], a);
        }
        __builtin_amdgcn_s_setprio(0);
        #pragma unroll
        for (int g = 0; g < 16; ++g) a[g] = gelu_fast(a[g]);
        #pragma unroll
        for (int sg = 0; sg < 2; ++sg){
            float xx[8];
            #pragma unroll
            for (int i = 0; i < 4; ++i){ xx[i] = a[sg*8+i]; xx[4+i] = a[sg*8+4+i]; }
            #pragma unroll
            for (int i = 0; i < 4; ++i) xpair(xx[i], xx[4+i], lh);
            const float* op = obrow + nt * 32 + sg * 16 + hf * 8;
            float4 o0 = *(const float4*)(op);
            float4 o1 = *(const float4*)(op + 4);
            xx[0]*=o0.x; xx[1]*=o0.y; xx[2]*=o0.z; xx[3]*=o0.w;
            xx[4]*=o1.x; xx[5]*=o1.y; xx[6]*=o1.z; xx[7]*=o1.w;
            split8(xx, ua[nt*2+sg], ul[nt*2+sg]);
        }
    }

    // ---- GEMM4 (swapped, fused, streamed): gelu -> exchange -> store
    const bool valid = (e0 < (long long)E);
    float* orow = out + e0 * HDIM;
    #pragma unroll
    for (int nt = 0; nt < 4; ++nt){
        const float* bb = bp + 320 + nt * 32 + hf * 16;
        f32x16 a;
        #pragma unroll
        for (int g = 0; g < 16; ++g) a[g] = bb[g];
        __builtin_amdgcn_s_setprio(1);
        #pragma unroll
        for (int ks = 0; ks < 8; ++ks){
            const v8s* wp = (const v8s*)(wf + 49152 + (nt * 8 + ks) * 1024);
            v8s bh = wp[lane], bl = wp[lane + 64];
            a = MFMA32(bh, ua[ks], a);
            a = MFMA32(bl, ua[ks], a);
            a = MFMA32(bh, ul[ks], a);
        }
        __builtin_amdgcn_s_setprio(0);
        #pragma unroll
        for (int g = 0; g < 16; ++g) a[g] = gelu_fast(a[g]);
        #pragma unroll
        for (int sg = 0; sg < 2; ++sg){
            float xx[8];
            #pragma unroll
            for (int i = 0; i < 4; ++i){ xx[i] = a[sg*8+i]; xx[4+i] = a[sg*8+4+i]; }
            #pragma unroll
            for (int i = 0; i < 4; ++i) xpair(xx[i], xx[4+i], lh);
            if (valid){
                float4 v0; v0.x=xx[0]; v0.y=xx[1]; v0.z=xx[2]; v0.w=xx[3];
                float4 v1; v1.x=xx[4]; v1.y=xx[5]; v1.z=xx[6]; v1.w=xx[7];
                float* dst = orow + nt * 32 + sg * 16 + hf * 8;
                *(float4*)(dst)     = v0;
                *(float4*)(dst + 4) = v1;
            }
        }
    }
}

extern "C" void kernel_launch(void* const* d_in, const int* in_sizes, int n_in,
                              void* d_out, int out_size, void* d_ws, size_t ws_size,
                              hipStream_t stream)
{
    (void)n_in; (void)out_size; (void)ws_size;   // requires ws_size >= 165632 B
    const float* known_mask   = (const float*)d_in[0];
    const int*   obs_idx      = (const int*)d_in[1];
    const int*   obs_mask_idx = (const int*)d_in[2];
    const int*   attr_idx     = (const int*)d_in[3];
    const float* obs_embs     = (const float*)d_in[4];
    const float* fea_corr     = (const float*)d_in[5];
    const float* W_rm1 = (const float*)d_in[6];
    const float* b_rm1 = (const float*)d_in[7];
    const float* W_rm2 = (const float*)d_in[8];
    const float* b_rm2 = (const float*)d_in[9];
    const float* W_rr  = (const float*)d_in[10];
    const float* b_rr  = (const float*)d_in[11];
    const float* W_rc  = (const float*)d_in[12];
    const float* b_rc  = (const float*)d_in[13];

    unsigned short* wf = (unsigned short*)d_ws;
    const int E = in_sizes[1];

    hipLaunchKernelGGL(prep_w, dim3(162), dim3(256), 0, stream,
                       W_rm1, W_rm2, W_rr, W_rc,
                       b_rm1, b_rm2, b_rr, b_rc, wf);

    const int ntiles = (E + 31) / 32;
    const int blocks = (ntiles + 3) / 4;   // 4 independent 1-wave tiles per 256-thread WG
    hipLaunchKernelGGL(arn_mfma, dim3(blocks), dim3(256), 0, stream,
                       known_mask, obs_idx, obs_mask_idx, attr_idx,
                       obs_embs, fea_corr,
                       wf, (float*)d_out, E);
}